// Round 15
// baseline (168.631 us; speedup 1.0000x reference)
//
#include <hip/hip_runtime.h>

typedef __attribute__((ext_vector_type(8))) __bf16 bf16x8;
typedef __attribute__((ext_vector_type(8))) unsigned short u16x8;
typedef __attribute__((ext_vector_type(4))) unsigned short u16x4;
typedef __attribute__((ext_vector_type(4))) float f32x4;

#define NEGV (-1e30f)

// ---------------------------------------------------------------------------
// Workspace layout (bytes):
//  Bh  : [1152][1024] bf16  @ 0          (2,359,296)
//  Bl  : [1152][1024] bf16  @ 2359296    (2,359,296)
//  LR  : [48][8192]  f32    @ 21495808   (1,572,864)
//  Vt  : [8][16][128][512] bf16 @ 23068672 (16,777,216)  written by mgemm
//  adjB: [16][512][512] u8  @ 39845888   (4,194,304)
//  total 44,040,192 B
// ---------------------------------------------------------------------------

__device__ __forceinline__ unsigned short f2bf(float f) {
    unsigned int u = __float_as_uint(f);
    u += 0x7fffu + ((u >> 16) & 1u);
    return (unsigned short)(u >> 16);
}
__device__ __forceinline__ float b2f(unsigned short h) {
    return __uint_as_float(((unsigned int)h) << 16);
}

// ---------------------------------------------------------------------------
// Kernel 1a: pack W_last columns via LDS transpose  [unchanged, verified]
// ---------------------------------------------------------------------------
__global__ __launch_bounds__(256) void pack_tr(const float* __restrict__ W,
                                               unsigned short* __restrict__ Bh,
                                               unsigned short* __restrict__ Bl) {
    __shared__ float tile[64 * 133];
    const int bid = blockIdx.x;
    const int kt = bid & 15, h = bid >> 4;
    const int k0 = kt * 64;
    const int tid = threadIdx.x;
    const float* wsrc = W + ((size_t)((h * 3 + 2) * 1024) + k0) * 128;

    #pragma unroll
    for (int rep = 0; rep < 8; ++rep) {
        int idx = rep * 256 + tid;
        int k = idx >> 5, dc = (idx & 31) * 4;
        float4 v = *(const float4*)(wsrc + (size_t)k * 128 + dc);
        tile[k * 133 + dc + 0] = v.x;
        tile[k * 133 + dc + 1] = v.y;
        tile[k * 133 + dc + 2] = v.z;
        tile[k * 133 + dc + 3] = v.w;
    }
    __syncthreads();
    #pragma unroll
    for (int rep = 0; rep < 4; ++rep) {
        int idx = rep * 256 + tid;
        int d = idx >> 3, kc = (idx & 7) * 8;
        u16x8 vh, vl;
        #pragma unroll
        for (int q = 0; q < 8; ++q) {
            float f = tile[(kc + q) * 133 + d];
            unsigned short hi = f2bf(f);
            vh[q] = hi;
            vl[q] = f2bf(f - b2f(hi));
        }
        size_t o = (size_t)(h * 128 + d) * 1024 + k0 + kc;
        *(u16x8*)(Bh + o) = vh;
        *(u16x8*)(Bl + o) = vl;
    }
}

// ---------------------------------------------------------------------------
// Kernel 1b: pack W.a columns  [unchanged, verified]
// ---------------------------------------------------------------------------
__global__ __launch_bounds__(256) void pack_wa(const float* __restrict__ W,
                                               const float* __restrict__ a1,
                                               const float* __restrict__ a2,
                                               unsigned short* __restrict__ Bh,
                                               unsigned short* __restrict__ Bl) {
    __shared__ float tile[64 * 133];
    const int bid = blockIdx.x;
    const int kt = bid & 15, ht = bid >> 4;
    const int h = ht & 7, t = ht >> 3;
    const int k0 = kt * 64;
    const int tid = threadIdx.x;
    const float* wsrc = W + ((size_t)((h * 3 + t) * 1024) + k0) * 128;

    #pragma unroll
    for (int rep = 0; rep < 8; ++rep) {
        int idx = rep * 256 + tid;
        int k = idx >> 5, dc = (idx & 31) * 4;
        float4 v = *(const float4*)(wsrc + (size_t)k * 128 + dc);
        tile[k * 133 + dc + 0] = v.x;
        tile[k * 133 + dc + 1] = v.y;
        tile[k * 133 + dc + 2] = v.z;
        tile[k * 133 + dc + 3] = v.w;
    }
    __syncthreads();
    if (tid < 128) {
        const int k = tid & 63, s = tid >> 6;
        const float* ar = (s ? a2 : a1) + (h * 3 + t) * 128;
        float acc = 0.f;
        #pragma unroll 4
        for (int d = 0; d < 128; ++d) acc += tile[k * 133 + d] * ar[d];
        unsigned short hi = f2bf(acc);
        size_t o = (size_t)(1024 + s * 24 + t * 8 + h) * 1024 + k0 + k;
        Bh[o] = hi;
        Bl[o] = f2bf(acc - b2f(hi));
    }
}

// ---------------------------------------------------------------------------
// Kernel 1c: zero pad columns 1072..1151  [unchanged]
// ---------------------------------------------------------------------------
__global__ __launch_bounds__(256) void pack_zero(unsigned short* __restrict__ Bh,
                                                 unsigned short* __restrict__ Bl) {
    const int n = 1072 + blockIdx.x;
    const int tid = threadIdx.x;
    *(unsigned long long*)(Bh + (size_t)n * 1024 + tid * 4) = 0ull;
    *(unsigned long long*)(Bl + (size_t)n * 1024 + tid * 4) = 0ull;
}

// ---------------------------------------------------------------------------
// Kernel 2: bf16x3 MFMA GEMM — r10/r14 structure widened to 8 waves/block
//   (512 thr), same 128x128 tile / 32KB LDS / staging pattern / barriers.
//   Wave w: wr=w>>1 (rows 32), wc=w&1 (cols 64); acc 2x4; 24 MFMA/step.
//   Resident waves/CU double (9 -> 18) at unchanged reuse -> latency hiding.
// ---------------------------------------------------------------------------
__global__ __launch_bounds__(512, 1) void mgemm(const float* __restrict__ X,
                                                const unsigned short* __restrict__ Bh,
                                                const unsigned short* __restrict__ Bl,
                                                const float* __restrict__ nm,
                                                unsigned short* __restrict__ Vt,
                                                float* __restrict__ LR) {
    __shared__ unsigned short Ah[128 * 32];
    __shared__ unsigned short Al[128 * 32];
    __shared__ unsigned short Bhs[128 * 32];
    __shared__ unsigned short Bls[128 * 32];

    const int bid = blockIdx.x;                 // 0..575
    const int swz = (bid & 7) * 72 + (bid >> 3); // XCD-aware, bijective
    const int nt = swz % 9, mt = swz / 9;
    const int n0 = nt * 128, m0 = mt * 128;

    const int tid = threadIdx.x;
    const int lane = tid & 63, w = tid >> 6;     // 8 waves
    const int wr = w >> 1, wc = w & 1;
    const int fr = lane & 15, fq = lane >> 4;

    f32x4 acc[2][4];
    #pragma unroll
    for (int m = 0; m < 2; ++m)
        #pragma unroll
        for (int n = 0; n < 4; ++n) acc[m][n] = (f32x4){0.f, 0.f, 0.f, 0.f};

    // A staging: row = tid>>2 (0..127), k-quarter = (tid&3)*8
    const int arow = tid >> 2, akq = (tid & 3) * 8;
    const float* xs = X + (size_t)(m0 + arow) * 1024 + akq;
    unsigned short* adh = Ah + arow * 32 + akq;
    unsigned short* adl = Al + arow * 32 + akq;

    // B staging: one gload_lds round per buffer (512 lanes x 16B = 8KB)
    const int brow = tid >> 2, bkb = tid & 3;
    const unsigned short* gbh = Bh + (size_t)(n0 + brow) * 1024 + bkb * 8;
    const unsigned short* gbl = Bl + (size_t)(n0 + brow) * 1024 + bkb * 8;
    unsigned short* dbh = Bhs + w * 512;   // wave-uniform base; +lane*16B implicit
    unsigned short* dbl = Bls + w * 512;

    for (int k0 = 0; k0 < 1024; k0 += 32) {
        __syncthreads();

        __builtin_amdgcn_global_load_lds(
            (const __attribute__((address_space(1))) void*)(gbh + k0),
            (__attribute__((address_space(3))) void*)dbh, 16, 0, 0);
        __builtin_amdgcn_global_load_lds(
            (const __attribute__((address_space(1))) void*)(gbl + k0),
            (__attribute__((address_space(3))) void*)dbl, 16, 0, 0);

        float4 xa = *(const float4*)(xs + k0);
        float4 xb = *(const float4*)(xs + k0 + 4);
        float xf[8] = {xa.x, xa.y, xa.z, xa.w, xb.x, xb.y, xb.z, xb.w};
        u16x8 vh, vl;
        #pragma unroll
        for (int i = 0; i < 8; ++i) {
            unsigned short hi = f2bf(xf[i]);
            vh[i] = hi;
            vl[i] = f2bf(xf[i] - b2f(hi));
        }
        *(u16x8*)(adh) = vh;
        *(u16x8*)(adl) = vl;

        __syncthreads();

        bf16x8 amh[2], bnh[4];
        #pragma unroll
        for (int m = 0; m < 2; ++m)
            amh[m] = *(bf16x8*)(Ah + (wr * 32 + m * 16 + fr) * 32 + fq * 8);
        #pragma unroll
        for (int n = 0; n < 4; ++n)
            bnh[n] = *(bf16x8*)(Bhs + (wc * 64 + n * 16 + fr) * 32 + fq * 8);
        #pragma unroll
        for (int m = 0; m < 2; ++m)
            #pragma unroll
            for (int n = 0; n < 4; ++n)
                acc[m][n] = __builtin_amdgcn_mfma_f32_16x16x32_bf16(amh[m], bnh[n], acc[m][n], 0, 0, 0);

        bf16x8 bnl[4];
        #pragma unroll
        for (int n = 0; n < 4; ++n)
            bnl[n] = *(bf16x8*)(Bls + (wc * 64 + n * 16 + fr) * 32 + fq * 8);
        #pragma unroll
        for (int m = 0; m < 2; ++m)
            #pragma unroll
            for (int n = 0; n < 4; ++n)
                acc[m][n] = __builtin_amdgcn_mfma_f32_16x16x32_bf16(amh[m], bnl[n], acc[m][n], 0, 0, 0);

        bf16x8 aml[2];
        #pragma unroll
        for (int m = 0; m < 2; ++m)
            aml[m] = *(bf16x8*)(Al + (wr * 32 + m * 16 + fr) * 32 + fq * 8);
        #pragma unroll
        for (int m = 0; m < 2; ++m)
            #pragma unroll
            for (int n = 0; n < 4; ++n)
                acc[m][n] = __builtin_amdgcn_mfma_f32_16x16x32_bf16(aml[m], bnh[n], acc[m][n], 0, 0, 0);
    }

    // ---- epilogue: C/D layout col=lane&15, row=(lane>>4)*4+reg
    if (nt < 8) {
        const int b_ = (mt * 128) >> 9;
        const int jb0 = (mt & 3) * 128;
        unsigned short* vtw = Vt + (size_t)(nt * 16 + b_) * 128 * 512;
        #pragma unroll
        for (int m = 0; m < 2; ++m) {
            const int rowb = wr * 32 + m * 16 + fq * 4;
            const int jb = jb0 + rowb;
            float mk[4];
            #pragma unroll
            for (int r = 0; r < 4; ++r) mk[r] = nm[m0 + rowb + r];
            #pragma unroll
            for (int n = 0; n < 4; ++n) {
                const int d = wc * 64 + n * 16 + fr;
                u16x4 pk;
                #pragma unroll
                for (int r = 0; r < 4; ++r) pk[r] = f2bf(acc[m][n][r] * mk[r]);
                *(u16x4*)(vtw + (size_t)d * 512 + jb) = pk;
            }
        }
    } else {
        #pragma unroll
        for (int m = 0; m < 2; ++m) {
            #pragma unroll
            for (int r = 0; r < 4; ++r) {
                const int R = m0 + wr * 32 + m * 16 + fq * 4 + r;
                #pragma unroll
                for (int n = 0; n < 4; ++n) {
                    const int c = wc * 64 + n * 16 + fr;
                    if (c < 48) LR[(size_t)c * 8192 + R] = acc[m][n][r];
                }
            }
        }
    }
}

// ---------------------------------------------------------------------------
// Kernel 3b: adj int32 -> byte array adjB  [unchanged]
// ---------------------------------------------------------------------------
__global__ __launch_bounds__(256) void adjb_kernel(const int* __restrict__ adj,
                                                   unsigned char* __restrict__ adjB) {
    const int idx = blockIdx.x * 256 + threadIdx.x;
    const int4* s = (const int4*)(adj + (size_t)idx * 16);
    int4 v0 = s[0], v1 = s[1], v2 = s[2], v3 = s[3];
    union { unsigned char c[16]; int4 v; } o;
    o.c[0] = (unsigned char)v0.x; o.c[1] = (unsigned char)v0.y;
    o.c[2] = (unsigned char)v0.z; o.c[3] = (unsigned char)v0.w;
    o.c[4] = (unsigned char)v1.x; o.c[5] = (unsigned char)v1.y;
    o.c[6] = (unsigned char)v1.z; o.c[7] = (unsigned char)v1.w;
    o.c[8] = (unsigned char)v2.x; o.c[9] = (unsigned char)v2.y;
    o.c[10] = (unsigned char)v2.z; o.c[11] = (unsigned char)v2.w;
    o.c[12] = (unsigned char)v3.x; o.c[13] = (unsigned char)v3.y;
    o.c[14] = (unsigned char)v3.z; o.c[15] = (unsigned char)v3.w;
    *(int4*)(adjB + (size_t)idx * 16) = o.v;
}

// ---------------------------------------------------------------------------
// Kernel 4: fused attn  [unchanged — verified]
// ---------------------------------------------------------------------------
__global__ __launch_bounds__(256, 4) void attn_kernel(const unsigned short* __restrict__ Vt,
                                                      const float* __restrict__ LR,
                                                      const unsigned char* __restrict__ adjB,
                                                      float* __restrict__ out) {
    __shared__ __align__(16) unsigned short Vb[2][16 * 512];
    __shared__ __align__(16) float rt[3 * 512];

    const int bid = blockIdx.x;
    const int itg = bid >> 7, hb = bid & 127, h = hb >> 4, b = hb & 15;
    const int tid = threadIdx.x, w = tid >> 6, lane = tid & 63;
    const int fr = lane & 15, fq = lane >> 4;
    const int i0 = (itg * 4 + w) * 16;
    const int fq8 = fq * 8;

    for (int idx = tid; idx < 1536; idx += 256) {
        int t = idx >> 9, j = idx & 511;
        rt[idx] = LR[(size_t)(24 + t * 8 + h) * 8192 + b * 512 + j];
    }
    const float lf0 = LR[(size_t)(h) * 8192 + b * 512 + i0 + fr];
    const float lf1 = LR[(size_t)(8 + h) * 8192 + b * 512 + i0 + fr];
    const float lf2 = LR[(size_t)(16 + h) * 8192 + b * 512 + i0 + fr];
    const unsigned char* arow = adjB + (size_t)(b * 512 + i0 + fr) * 512;
    const unsigned short* vt = Vt + (size_t)(h * 16 + b) * 128 * 512;

#define STAGE_V(bufp, os_) do {                                                   \
        _Pragma("unroll")                                                          \
        for (int q_ = 0; q_ < 4; ++q_) {                                           \
            const int nh_ = q_ * 4 + w;                                            \
            const unsigned short* src_ = vt + (size_t)((nh_ >> 1) * 16 + fr) * 512 \
                                          + (os_) * 64 + (nh_ & 1) * 32 + fq8;     \
            unsigned short* dst_ = (bufp) + nh_ * 512;                             \
            __builtin_amdgcn_global_load_lds(                                      \
                (const __attribute__((address_space(1))) void*)src_,               \
                (__attribute__((address_space(3))) void*)dst_, 16, 0, 0);          \
        }                                                                          \
    } while (0)

    STAGE_V(&Vb[0][0], 0);
    uint2 aA = *(const uint2*)(arow + fq8);
    uint2 aB = *(const uint2*)(arow + fq8 + 32);

    f32x4 acc[8];
    #pragma unroll
    for (int n = 0; n < 8; ++n) acc[n] = (f32x4){0.f, 0.f, 0.f, 0.f};
    float rsum = 0.f;

    __syncthreads();

    #pragma unroll 1
    for (int os = 0; os < 8; ++os) {
        unsigned short* vb = &Vb[os & 1][0];
        if (os < 7) STAGE_V(&Vb[(os & 1) ^ 1][0], os + 1);

        const int jA = os * 64 + fq8;
        const int jB = jA + 32;

        u16x8 vhA, vlA, vhB, vlB;
        {
            float4 r0a = *(const float4*)(rt + jA), r0b = *(const float4*)(rt + jA + 4);
            float4 r1a = *(const float4*)(rt + 512 + jA), r1b = *(const float4*)(rt + 512 + jA + 4);
            float4 r2a = *(const float4*)(rt + 1024 + jA), r2b = *(const float4*)(rt + 1024 + jA + 4);
            float e0[8] = {r0a.x, r0a.y, r0a.z, r0a.w, r0b.x, r0b.y, r0b.z, r0b.w};
            float e1[8] = {r1a.x, r1a.y, r1a.z, r1a.w, r1b.x, r1b.y, r1b.z, r1b.w};
            float e2[8] = {r2a.x, r2a.y, r2a.z, r2a.w, r2b.x, r2b.y, r2b.z, r2b.w};
            #pragma unroll
            for (int q = 0; q < 8; ++q) {
                unsigned av = ((q < 4 ? aA.x : aA.y) >> (8 * (q & 3))) & 255u;
                float sb = (av == 1u) ? (lf0 + e0[q])
                         : (av == 2u) ? (lf1 + e1[q]) : (lf2 + e2[q]);
                float sv = fmaxf(sb, 0.f) + 0.2f * fminf(sb, 0.f);
                float p = (av != 0u) ? __expf(sv) : 0.f;
                rsum += p;
                unsigned short hi = f2bf(p);
                vhA[q] = hi;
                vlA[q] = f2bf(p - b2f(hi));
            }
        }
        {
            float4 r0a = *(const float4*)(rt + jB), r0b = *(const float4*)(rt + jB + 4);
            float4 r1a = *(const float4*)(rt + 512 + jB), r1b = *(const float4*)(rt + 512 + jB + 4);
            float4 r2a = *(const float4*)(rt + 1024 + jB), r2b = *(const float4*)(rt + 1024 + jB + 4);
            float e0[8] = {r0a.x, r0a.y, r0a.z, r0a.w, r0b.x, r0b.y, r0b.z, r0b.w};
            float e1[8] = {r1a.x, r1a.y, r1a.z, r1a.w, r1b.x, r1b.y, r1b.z, r1b.w};
            float e2[8] = {r2a.x, r2a.y, r2a.z, r2a.w, r2b.x, r2b.y, r2b.z, r2b.w};
            #pragma unroll
            for (int q = 0; q < 8; ++q) {
                unsigned av = ((q < 4 ? aB.x : aB.y) >> (8 * (q & 3))) & 255u;
                float sb = (av == 1u) ? (lf0 + e0[q])
                         : (av == 2u) ? (lf1 + e1[q]) : (lf2 + e2[q]);
                float sv = fmaxf(sb, 0.f) + 0.2f * fminf(sb, 0.f);
                float p = (av != 0u) ? __expf(sv) : 0.f;
                rsum += p;
                unsigned short hi = f2bf(p);
                vhB[q] = hi;
                vlB[q] = f2bf(p - b2f(hi));
            }
        }
        if (os < 7) {
            aA = *(const uint2*)(arow + (os + 1) * 64 + fq8);
            aB = *(const uint2*)(arow + (os + 1) * 64 + fq8 + 32);
        }

        bf16x8 ahA = *(bf16x8*)&vhA, alA = *(bf16x8*)&vlA;
        bf16x8 ahB = *(bf16x8*)&vhB, alB = *(bf16x8*)&vlB;

        #pragma unroll
        for (int n = 0; n < 8; ++n) {
            bf16x8 vA = *(bf16x8*)(vb + (n * 2 + 0) * 512 + lane * 8);
            bf16x8 vB = *(bf16x8*)(vb + (n * 2 + 1) * 512 + lane * 8);
            acc[n] = __builtin_amdgcn_mfma_f32_16x16x32_bf16(ahA, vA, acc[n], 0, 0, 0);
            acc[n] = __builtin_amdgcn_mfma_f32_16x16x32_bf16(alA, vA, acc[n], 0, 0, 0);
            acc[n] = __builtin_amdgcn_mfma_f32_16x16x32_bf16(ahB, vB, acc[n], 0, 0, 0);
            acc[n] = __builtin_amdgcn_mfma_f32_16x16x32_bf16(alB, vB, acc[n], 0, 0, 0);
        }
        __syncthreads();
    }
#undef STAGE_V

    rsum += __shfl_xor(rsum, 16);
    rsum += __shfl_xor(rsum, 32);

    #pragma unroll
    for (int rr = 0; rr < 4; ++rr) {
        const int row = fq * 4 + rr;
        const float inv = 1.0f / __shfl(rsum, row);
        #pragma unroll
        for (int n = 0; n < 8; ++n) {
            out[(size_t)(b * 512 + i0 + row) * 1024 + h * 128 + n * 16 + fr] =
                fmaxf(acc[n][rr] * inv, 0.f);
        }
    }
}

// ---------------------------------------------------------------------------
extern "C" void kernel_launch(void* const* d_in, const int* in_sizes, int n_in,
                              void* d_out, int out_size, void* d_ws, size_t ws_size,
                              hipStream_t stream) {
    const float* x   = (const float*)d_in[0];
    const int*   adj = (const int*)d_in[1];
    const float* nm  = (const float*)d_in[2];
    const float* W   = (const float*)d_in[3];
    const float* a1  = (const float*)d_in[4];
    const float* a2  = (const float*)d_in[5];
    float* out = (float*)d_out;
    char* wsb = (char*)d_ws;

    unsigned short* Bh   = (unsigned short*)(wsb);
    unsigned short* Bl   = (unsigned short*)(wsb + 2359296);
    float*          LR   = (float*)(wsb + 21495808);
    unsigned short* Vt   = (unsigned short*)(wsb + 23068672);
    unsigned char*  adjB = (unsigned char*)(wsb + 39845888);

    hipLaunchKernelGGL(adjb_kernel, dim3(1024), dim3(256), 0, stream, adj, adjB);
    hipLaunchKernelGGL(pack_tr, dim3(128), dim3(256), 0, stream, W, Bh, Bl);
    hipLaunchKernelGGL(pack_wa, dim3(384), dim3(256), 0, stream, W, a1, a2, Bh, Bl);
    hipLaunchKernelGGL(pack_zero, dim3(80), dim3(256), 0, stream, Bh, Bl);
    hipLaunchKernelGGL(mgemm, dim3(576), dim3(512), 0, stream, x, Bh, Bl, nm, Vt, LR);
    hipLaunchKernelGGL(attn_kernel, dim3(1024), dim3(256), 0, stream, Vt, LR, adjB, out);
}

// Round 16
// 146.519 us; speedup vs baseline: 1.1509x; 1.1509x over previous
//
#include <hip/hip_runtime.h>

typedef __attribute__((ext_vector_type(8))) __bf16 bf16x8;
typedef __attribute__((ext_vector_type(8))) unsigned short u16x8;
typedef __attribute__((ext_vector_type(4))) unsigned short u16x4;
typedef __attribute__((ext_vector_type(4))) float f32x4;

#define NEGV (-1e30f)

// ---------------------------------------------------------------------------
// Workspace layout (bytes):
//  Bh  : [1152][1024] bf16  @ 0          (2,359,296)
//  Bl  : [1152][1024] bf16  @ 2359296    (2,359,296)
//  LR  : [48][8192]  f32    @ 21495808   (1,572,864)
//  Vt  : [8][16][128][512] bf16 @ 23068672 (16,777,216)  written by mgemm
//  adjB: [16][512][512] u8  @ 39845888   (4,194,304)
//  total 44,040,192 B
// ---------------------------------------------------------------------------

__device__ __forceinline__ unsigned short f2bf(float f) {
    unsigned int u = __float_as_uint(f);
    u += 0x7fffu + ((u >> 16) & 1u);
    return (unsigned short)(u >> 16);
}
__device__ __forceinline__ float b2f(unsigned short h) {
    return __uint_as_float(((unsigned int)h) << 16);
}

// ---------------------------------------------------------------------------
// Kernel 1a: pack W_last columns via LDS transpose  [r14-verified]
// ---------------------------------------------------------------------------
__global__ __launch_bounds__(256) void pack_tr(const float* __restrict__ W,
                                               unsigned short* __restrict__ Bh,
                                               unsigned short* __restrict__ Bl) {
    __shared__ float tile[64 * 133];
    const int bid = blockIdx.x;
    const int kt = bid & 15, h = bid >> 4;
    const int k0 = kt * 64;
    const int tid = threadIdx.x;
    const float* wsrc = W + ((size_t)((h * 3 + 2) * 1024) + k0) * 128;

    #pragma unroll
    for (int rep = 0; rep < 8; ++rep) {
        int idx = rep * 256 + tid;
        int k = idx >> 5, dc = (idx & 31) * 4;
        float4 v = *(const float4*)(wsrc + (size_t)k * 128 + dc);
        tile[k * 133 + dc + 0] = v.x;
        tile[k * 133 + dc + 1] = v.y;
        tile[k * 133 + dc + 2] = v.z;
        tile[k * 133 + dc + 3] = v.w;
    }
    __syncthreads();
    #pragma unroll
    for (int rep = 0; rep < 4; ++rep) {
        int idx = rep * 256 + tid;
        int d = idx >> 3, kc = (idx & 7) * 8;
        u16x8 vh, vl;
        #pragma unroll
        for (int q = 0; q < 8; ++q) {
            float f = tile[(kc + q) * 133 + d];
            unsigned short hi = f2bf(f);
            vh[q] = hi;
            vl[q] = f2bf(f - b2f(hi));
        }
        size_t o = (size_t)(h * 128 + d) * 1024 + k0 + kc;
        *(u16x8*)(Bh + o) = vh;
        *(u16x8*)(Bl + o) = vl;
    }
}

// ---------------------------------------------------------------------------
// Kernel 1b: pack W.a columns  [r14-verified]
// ---------------------------------------------------------------------------
__global__ __launch_bounds__(256) void pack_wa(const float* __restrict__ W,
                                               const float* __restrict__ a1,
                                               const float* __restrict__ a2,
                                               unsigned short* __restrict__ Bh,
                                               unsigned short* __restrict__ Bl) {
    __shared__ float tile[64 * 133];
    const int bid = blockIdx.x;
    const int kt = bid & 15, ht = bid >> 4;
    const int h = ht & 7, t = ht >> 3;
    const int k0 = kt * 64;
    const int tid = threadIdx.x;
    const float* wsrc = W + ((size_t)((h * 3 + t) * 1024) + k0) * 128;

    #pragma unroll
    for (int rep = 0; rep < 8; ++rep) {
        int idx = rep * 256 + tid;
        int k = idx >> 5, dc = (idx & 31) * 4;
        float4 v = *(const float4*)(wsrc + (size_t)k * 128 + dc);
        tile[k * 133 + dc + 0] = v.x;
        tile[k * 133 + dc + 1] = v.y;
        tile[k * 133 + dc + 2] = v.z;
        tile[k * 133 + dc + 3] = v.w;
    }
    __syncthreads();
    if (tid < 128) {
        const int k = tid & 63, s = tid >> 6;
        const float* ar = (s ? a2 : a1) + (h * 3 + t) * 128;
        float acc = 0.f;
        #pragma unroll 4
        for (int d = 0; d < 128; ++d) acc += tile[k * 133 + d] * ar[d];
        unsigned short hi = f2bf(acc);
        size_t o = (size_t)(1024 + s * 24 + t * 8 + h) * 1024 + k0 + k;
        Bh[o] = hi;
        Bl[o] = f2bf(acc - b2f(hi));
    }
}

// ---------------------------------------------------------------------------
// Kernel 1c: zero pad columns 1072..1151  [r14-verified]
// ---------------------------------------------------------------------------
__global__ __launch_bounds__(256) void pack_zero(unsigned short* __restrict__ Bh,
                                                 unsigned short* __restrict__ Bl) {
    const int n = 1072 + blockIdx.x;
    const int tid = threadIdx.x;
    *(unsigned long long*)(Bh + (size_t)n * 1024 + tid * 4) = 0ull;
    *(unsigned long long*)(Bl + (size_t)n * 1024 + tid * 4) = 0ull;
}

// ---------------------------------------------------------------------------
// Kernel 2: bf16x3 MFMA GEMM — r14-exact (proven 89us): 128x128 tile, 4 waves,
//   2-barrier loop, Vt-direct epilogue.
// ---------------------------------------------------------------------------
__global__ __launch_bounds__(256, 3) void mgemm(const float* __restrict__ X,
                                                const unsigned short* __restrict__ Bh,
                                                const unsigned short* __restrict__ Bl,
                                                const float* __restrict__ nm,
                                                unsigned short* __restrict__ Vt,
                                                float* __restrict__ LR) {
    __shared__ unsigned short Ah[128 * 32];
    __shared__ unsigned short Al[128 * 32];
    __shared__ unsigned short Bhs[128 * 32];
    __shared__ unsigned short Bls[128 * 32];

    const int bid = blockIdx.x;                 // 0..575
    const int swz = (bid & 7) * 72 + (bid >> 3); // XCD-aware, bijective
    const int nt = swz % 9, mt = swz / 9;
    const int n0 = nt * 128, m0 = mt * 128;

    const int tid = threadIdx.x;
    const int lane = tid & 63, w = tid >> 6;
    const int wr = w >> 1, wc = w & 1;
    const int fr = lane & 15, fq = lane >> 4;

    f32x4 acc[4][4];
    #pragma unroll
    for (int m = 0; m < 4; ++m)
        #pragma unroll
        for (int n = 0; n < 4; ++n) acc[m][n] = (f32x4){0.f, 0.f, 0.f, 0.f};

    const int arow = tid >> 1, ahalf = tid & 1;
    const float* xs = X + (size_t)(m0 + arow) * 1024 + ahalf * 16;
    unsigned short* adh = Ah + arow * 32 + ahalf * 16;
    unsigned short* adl = Al + arow * 32 + ahalf * 16;

    for (int k0 = 0; k0 < 1024; k0 += 32) {
        __syncthreads();

        #pragma unroll
        for (int q = 0; q < 2; ++q) {
            const int s = q * 256 + tid;
            const int brow = s >> 2, bkb = s & 3;
            const unsigned short* gh = Bh + (size_t)(n0 + brow) * 1024 + k0 + bkb * 8;
            const unsigned short* gl = Bl + (size_t)(n0 + brow) * 1024 + k0 + bkb * 8;
            unsigned short* dh = Bhs + (q * 256 + w * 64) * 8;
            unsigned short* dl = Bls + (q * 256 + w * 64) * 8;
            __builtin_amdgcn_global_load_lds(
                (const __attribute__((address_space(1))) void*)gh,
                (__attribute__((address_space(3))) void*)dh, 16, 0, 0);
            __builtin_amdgcn_global_load_lds(
                (const __attribute__((address_space(1))) void*)gl,
                (__attribute__((address_space(3))) void*)dl, 16, 0, 0);
        }

        float xf[16];
        #pragma unroll
        for (int i = 0; i < 4; ++i) {
            float4 v = *(const float4*)(xs + k0 + i * 4);
            xf[i * 4 + 0] = v.x; xf[i * 4 + 1] = v.y;
            xf[i * 4 + 2] = v.z; xf[i * 4 + 3] = v.w;
        }
        u16x8 vh0, vh1, vl0, vl1;
        #pragma unroll
        for (int i = 0; i < 8; ++i) {
            unsigned short hi = f2bf(xf[i]);
            vh0[i] = hi;
            vl0[i] = f2bf(xf[i] - b2f(hi));
        }
        #pragma unroll
        for (int i = 0; i < 8; ++i) {
            unsigned short hi = f2bf(xf[8 + i]);
            vh1[i] = hi;
            vl1[i] = f2bf(xf[8 + i] - b2f(hi));
        }
        *(u16x8*)(adh) = vh0;
        *(u16x8*)(adh + 8) = vh1;
        *(u16x8*)(adl) = vl0;
        *(u16x8*)(adl + 8) = vl1;

        __syncthreads();

        bf16x8 amh[4], bnh[4];
        #pragma unroll
        for (int m = 0; m < 4; ++m)
            amh[m] = *(bf16x8*)(Ah + (wr * 64 + m * 16 + fr) * 32 + fq * 8);
        #pragma unroll
        for (int n = 0; n < 4; ++n)
            bnh[n] = *(bf16x8*)(Bhs + (wc * 64 + n * 16 + fr) * 32 + fq * 8);
        #pragma unroll
        for (int m = 0; m < 4; ++m)
            #pragma unroll
            for (int n = 0; n < 4; ++n)
                acc[m][n] = __builtin_amdgcn_mfma_f32_16x16x32_bf16(amh[m], bnh[n], acc[m][n], 0, 0, 0);

        bf16x8 bnl[4];
        #pragma unroll
        for (int n = 0; n < 4; ++n)
            bnl[n] = *(bf16x8*)(Bls + (wc * 64 + n * 16 + fr) * 32 + fq * 8);
        #pragma unroll
        for (int m = 0; m < 4; ++m)
            #pragma unroll
            for (int n = 0; n < 4; ++n)
                acc[m][n] = __builtin_amdgcn_mfma_f32_16x16x32_bf16(amh[m], bnl[n], acc[m][n], 0, 0, 0);

        bf16x8 aml[4];
        #pragma unroll
        for (int m = 0; m < 4; ++m)
            aml[m] = *(bf16x8*)(Al + (wr * 64 + m * 16 + fr) * 32 + fq * 8);
        #pragma unroll
        for (int m = 0; m < 4; ++m)
            #pragma unroll
            for (int n = 0; n < 4; ++n)
                acc[m][n] = __builtin_amdgcn_mfma_f32_16x16x32_bf16(aml[m], bnh[n], acc[m][n], 0, 0, 0);
    }

    // ---- epilogue: C/D layout col=lane&15, row=(lane>>4)*4+reg
    if (nt < 8) {
        const int b_ = (mt * 128) >> 9;
        const int jb0 = (mt & 3) * 128;
        unsigned short* vtw = Vt + (size_t)(nt * 16 + b_) * 128 * 512;
        #pragma unroll
        for (int m = 0; m < 4; ++m) {
            const int jb = jb0 + wr * 64 + m * 16 + fq * 4;
            float mk[4];
            #pragma unroll
            for (int r = 0; r < 4; ++r)
                mk[r] = nm[m0 + wr * 64 + m * 16 + fq * 4 + r];
            #pragma unroll
            for (int n = 0; n < 4; ++n) {
                const int d = wc * 64 + n * 16 + fr;
                u16x4 pk;
                #pragma unroll
                for (int r = 0; r < 4; ++r) pk[r] = f2bf(acc[m][n][r] * mk[r]);
                *(u16x4*)(vtw + (size_t)d * 512 + jb) = pk;
            }
        }
    } else {
        #pragma unroll
        for (int m = 0; m < 4; ++m) {
            #pragma unroll
            for (int r = 0; r < 4; ++r) {
                const int R = m0 + wr * 64 + m * 16 + fq * 4 + r;
                #pragma unroll
                for (int n = 0; n < 4; ++n) {
                    const int c = wc * 64 + n * 16 + fr;
                    if (c < 48) LR[(size_t)c * 8192 + R] = acc[m][n][r];
                }
            }
        }
    }
}

// ---------------------------------------------------------------------------
// Kernel 3b: adj int32 -> byte array adjB  [verified]
// ---------------------------------------------------------------------------
__global__ __launch_bounds__(256) void adjb_kernel(const int* __restrict__ adj,
                                                   unsigned char* __restrict__ adjB) {
    const int idx = blockIdx.x * 256 + threadIdx.x;
    const int4* s = (const int4*)(adj + (size_t)idx * 16);
    int4 v0 = s[0], v1 = s[1], v2 = s[2], v3 = s[3];
    union { unsigned char c[16]; int4 v; } o;
    o.c[0] = (unsigned char)v0.x; o.c[1] = (unsigned char)v0.y;
    o.c[2] = (unsigned char)v0.z; o.c[3] = (unsigned char)v0.w;
    o.c[4] = (unsigned char)v1.x; o.c[5] = (unsigned char)v1.y;
    o.c[6] = (unsigned char)v1.z; o.c[7] = (unsigned char)v1.w;
    o.c[8] = (unsigned char)v2.x; o.c[9] = (unsigned char)v2.y;
    o.c[10] = (unsigned char)v2.z; o.c[11] = (unsigned char)v2.w;
    o.c[12] = (unsigned char)v3.x; o.c[13] = (unsigned char)v3.y;
    o.c[14] = (unsigned char)v3.z; o.c[15] = (unsigned char)v3.w;
    *(int4*)(adjB + (size_t)idx * 16) = o.v;
}

// ---------------------------------------------------------------------------
// Kernel 4: fused attn  [verified]
// ---------------------------------------------------------------------------
__global__ __launch_bounds__(256, 4) void attn_kernel(const unsigned short* __restrict__ Vt,
                                                      const float* __restrict__ LR,
                                                      const unsigned char* __restrict__ adjB,
                                                      float* __restrict__ out) {
    __shared__ __align__(16) unsigned short Vb[2][16 * 512];
    __shared__ __align__(16) float rt[3 * 512];

    const int bid = blockIdx.x;
    const int itg = bid >> 7, hb = bid & 127, h = hb >> 4, b = hb & 15;
    const int tid = threadIdx.x, w = tid >> 6, lane = tid & 63;
    const int fr = lane & 15, fq = lane >> 4;
    const int i0 = (itg * 4 + w) * 16;
    const int fq8 = fq * 8;

    for (int idx = tid; idx < 1536; idx += 256) {
        int t = idx >> 9, j = idx & 511;
        rt[idx] = LR[(size_t)(24 + t * 8 + h) * 8192 + b * 512 + j];
    }
    const float lf0 = LR[(size_t)(h) * 8192 + b * 512 + i0 + fr];
    const float lf1 = LR[(size_t)(8 + h) * 8192 + b * 512 + i0 + fr];
    const float lf2 = LR[(size_t)(16 + h) * 8192 + b * 512 + i0 + fr];
    const unsigned char* arow = adjB + (size_t)(b * 512 + i0 + fr) * 512;
    const unsigned short* vt = Vt + (size_t)(h * 16 + b) * 128 * 512;

#define STAGE_V(bufp, os_) do {                                                   \
        _Pragma("unroll")                                                          \
        for (int q_ = 0; q_ < 4; ++q_) {                                           \
            const int nh_ = q_ * 4 + w;                                            \
            const unsigned short* src_ = vt + (size_t)((nh_ >> 1) * 16 + fr) * 512 \
                                          + (os_) * 64 + (nh_ & 1) * 32 + fq8;     \
            unsigned short* dst_ = (bufp) + nh_ * 512;                             \
            __builtin_amdgcn_global_load_lds(                                      \
                (const __attribute__((address_space(1))) void*)src_,               \
                (__attribute__((address_space(3))) void*)dst_, 16, 0, 0);          \
        }                                                                          \
    } while (0)

    STAGE_V(&Vb[0][0], 0);
    uint2 aA = *(const uint2*)(arow + fq8);
    uint2 aB = *(const uint2*)(arow + fq8 + 32);

    f32x4 acc[8];
    #pragma unroll
    for (int n = 0; n < 8; ++n) acc[n] = (f32x4){0.f, 0.f, 0.f, 0.f};
    float rsum = 0.f;

    __syncthreads();

    #pragma unroll 1
    for (int os = 0; os < 8; ++os) {
        unsigned short* vb = &Vb[os & 1][0];
        if (os < 7) STAGE_V(&Vb[(os & 1) ^ 1][0], os + 1);

        const int jA = os * 64 + fq8;
        const int jB = jA + 32;

        u16x8 vhA, vlA, vhB, vlB;
        {
            float4 r0a = *(const float4*)(rt + jA), r0b = *(const float4*)(rt + jA + 4);
            float4 r1a = *(const float4*)(rt + 512 + jA), r1b = *(const float4*)(rt + 512 + jA + 4);
            float4 r2a = *(const float4*)(rt + 1024 + jA), r2b = *(const float4*)(rt + 1024 + jA + 4);
            float e0[8] = {r0a.x, r0a.y, r0a.z, r0a.w, r0b.x, r0b.y, r0b.z, r0b.w};
            float e1[8] = {r1a.x, r1a.y, r1a.z, r1a.w, r1b.x, r1b.y, r1b.z, r1b.w};
            float e2[8] = {r2a.x, r2a.y, r2a.z, r2a.w, r2b.x, r2b.y, r2b.z, r2b.w};
            #pragma unroll
            for (int q = 0; q < 8; ++q) {
                unsigned av = ((q < 4 ? aA.x : aA.y) >> (8 * (q & 3))) & 255u;
                float sb = (av == 1u) ? (lf0 + e0[q])
                         : (av == 2u) ? (lf1 + e1[q]) : (lf2 + e2[q]);
                float sv = fmaxf(sb, 0.f) + 0.2f * fminf(sb, 0.f);
                float p = (av != 0u) ? __expf(sv) : 0.f;
                rsum += p;
                unsigned short hi = f2bf(p);
                vhA[q] = hi;
                vlA[q] = f2bf(p - b2f(hi));
            }
        }
        {
            float4 r0a = *(const float4*)(rt + jB), r0b = *(const float4*)(rt + jB + 4);
            float4 r1a = *(const float4*)(rt + 512 + jB), r1b = *(const float4*)(rt + 512 + jB + 4);
            float4 r2a = *(const float4*)(rt + 1024 + jB), r2b = *(const float4*)(rt + 1024 + jB + 4);
            float e0[8] = {r0a.x, r0a.y, r0a.z, r0a.w, r0b.x, r0b.y, r0b.z, r0b.w};
            float e1[8] = {r1a.x, r1a.y, r1a.z, r1a.w, r1b.x, r1b.y, r1b.z, r1b.w};
            float e2[8] = {r2a.x, r2a.y, r2a.z, r2a.w, r2b.x, r2b.y, r2b.z, r2b.w};
            #pragma unroll
            for (int q = 0; q < 8; ++q) {
                unsigned av = ((q < 4 ? aB.x : aB.y) >> (8 * (q & 3))) & 255u;
                float sb = (av == 1u) ? (lf0 + e0[q])
                         : (av == 2u) ? (lf1 + e1[q]) : (lf2 + e2[q]);
                float sv = fmaxf(sb, 0.f) + 0.2f * fminf(sb, 0.f);
                float p = (av != 0u) ? __expf(sv) : 0.f;
                rsum += p;
                unsigned short hi = f2bf(p);
                vhB[q] = hi;
                vlB[q] = f2bf(p - b2f(hi));
            }
        }
        if (os < 7) {
            aA = *(const uint2*)(arow + (os + 1) * 64 + fq8);
            aB = *(const uint2*)(arow + (os + 1) * 64 + fq8 + 32);
        }

        bf16x8 ahA = *(bf16x8*)&vhA, alA = *(bf16x8*)&vlA;
        bf16x8 ahB = *(bf16x8*)&vhB, alB = *(bf16x8*)&vlB;

        #pragma unroll
        for (int n = 0; n < 8; ++n) {
            bf16x8 vA = *(bf16x8*)(vb + (n * 2 + 0) * 512 + lane * 8);
            bf16x8 vB = *(bf16x8*)(vb + (n * 2 + 1) * 512 + lane * 8);
            acc[n] = __builtin_amdgcn_mfma_f32_16x16x32_bf16(ahA, vA, acc[n], 0, 0, 0);
            acc[n] = __builtin_amdgcn_mfma_f32_16x16x32_bf16(alA, vA, acc[n], 0, 0, 0);
            acc[n] = __builtin_amdgcn_mfma_f32_16x16x32_bf16(ahB, vB, acc[n], 0, 0, 0);
            acc[n] = __builtin_amdgcn_mfma_f32_16x16x32_bf16(alB, vB, acc[n], 0, 0, 0);
        }
        __syncthreads();
    }
#undef STAGE_V

    rsum += __shfl_xor(rsum, 16);
    rsum += __shfl_xor(rsum, 32);

    #pragma unroll
    for (int rr = 0; rr < 4; ++rr) {
        const int row = fq * 4 + rr;
        const float inv = 1.0f / __shfl(rsum, row);
        #pragma unroll
        for (int n = 0; n < 8; ++n) {
            out[(size_t)(b * 512 + i0 + row) * 1024 + h * 128 + n * 16 + fr] =
                fmaxf(acc[n][rr] * inv, 0.f);
        }
    }
}

// ---------------------------------------------------------------------------
extern "C" void kernel_launch(void* const* d_in, const int* in_sizes, int n_in,
                              void* d_out, int out_size, void* d_ws, size_t ws_size,
                              hipStream_t stream) {
    const float* x   = (const float*)d_in[0];
    const int*   adj = (const int*)d_in[1];
    const float* nm  = (const float*)d_in[2];
    const float* W   = (const float*)d_in[3];
    const float* a1  = (const float*)d_in[4];
    const float* a2  = (const float*)d_in[5];
    float* out = (float*)d_out;
    char* wsb = (char*)d_ws;

    unsigned short* Bh   = (unsigned short*)(wsb);
    unsigned short* Bl   = (unsigned short*)(wsb + 2359296);
    float*          LR   = (float*)(wsb + 21495808);
    unsigned short* Vt   = (unsigned short*)(wsb + 23068672);
    unsigned char*  adjB = (unsigned char*)(wsb + 39845888);

    hipLaunchKernelGGL(adjb_kernel, dim3(1024), dim3(256), 0, stream, adj, adjB);
    hipLaunchKernelGGL(pack_tr, dim3(128), dim3(256), 0, stream, W, Bh, Bl);
    hipLaunchKernelGGL(pack_wa, dim3(384), dim3(256), 0, stream, W, a1, a2, Bh, Bl);
    hipLaunchKernelGGL(pack_zero, dim3(80), dim3(256), 0, stream, Bh, Bl);
    hipLaunchKernelGGL(mgemm, dim3(576), dim3(256), 0, stream, x, Bh, Bl, nm, Vt, LR);
    hipLaunchKernelGGL(attn_kernel, dim3(1024), dim3(256), 0, stream, Vt, LR, adjB, out);
}

// Round 17
// 134.663 us; speedup vs baseline: 1.2522x; 1.0880x over previous
//
#include <hip/hip_runtime.h>

typedef __attribute__((ext_vector_type(8))) __bf16 bf16x8;
typedef __attribute__((ext_vector_type(8))) unsigned short u16x8;
typedef __attribute__((ext_vector_type(4))) unsigned short u16x4;
typedef __attribute__((ext_vector_type(4))) float f32x4;

#define NEGV (-1e30f)

// ---------------------------------------------------------------------------
// Workspace layout (bytes):
//  Bh  : [1152][1024] bf16  @ 0          (2,359,296)
//  Bl  : [1152][1024] bf16  @ 2359296    (2,359,296)
//  LR  : [48][8192]  f32    @ 21495808   (1,572,864)
//  Vt  : [8][16][128][512] bf16 @ 23068672 (16,777,216)  written by mgemm
//  adjB: [16][512][512] u8  @ 39845888   (4,194,304)
//  total 44,040,192 B
// ---------------------------------------------------------------------------

__device__ __forceinline__ unsigned short f2bf(float f) {
    unsigned int u = __float_as_uint(f);
    u += 0x7fffu + ((u >> 16) & 1u);
    return (unsigned short)(u >> 16);
}
__device__ __forceinline__ float b2f(unsigned short h) {
    return __uint_as_float(((unsigned int)h) << 16);
}
// RNE via hardware cvt (compiler emits v_cvt_pk_bf16_f32 for pairs).
// Bitwise-identical to f2bf on finite non-NaN inputs.
__device__ __forceinline__ unsigned short f2bf_rn(float f) {
    union { __bf16 b; unsigned short u; } c;
    c.b = (__bf16)f;
    return c.u;
}

// ---------------------------------------------------------------------------
// Kernel 1: fused pack (tr + wa + zero).  grid 592:
//   bid <128       : W_last columns via LDS transpose (coalesced W reads)
//   128<=bid<512   : W.a columns via LDS-staged matvec
//   bid>=512       : zero pad columns 1072..1151
// ---------------------------------------------------------------------------
__global__ __launch_bounds__(256) void pack_all(const float* __restrict__ W,
                                                const float* __restrict__ a1,
                                                const float* __restrict__ a2,
                                                unsigned short* __restrict__ Bh,
                                                unsigned short* __restrict__ Bl) {
    __shared__ float tile[64 * 133];
    const int bid = blockIdx.x;
    const int tid = threadIdx.x;

    if (bid < 128) {
        const int kt = bid & 15, h = bid >> 4;
        const int k0 = kt * 64;
        const float* wsrc = W + ((size_t)((h * 3 + 2) * 1024) + k0) * 128;

        #pragma unroll
        for (int rep = 0; rep < 8; ++rep) {
            int idx = rep * 256 + tid;
            int k = idx >> 5, dc = (idx & 31) * 4;
            float4 v = *(const float4*)(wsrc + (size_t)k * 128 + dc);
            tile[k * 133 + dc + 0] = v.x;
            tile[k * 133 + dc + 1] = v.y;
            tile[k * 133 + dc + 2] = v.z;
            tile[k * 133 + dc + 3] = v.w;
        }
        __syncthreads();
        #pragma unroll
        for (int rep = 0; rep < 4; ++rep) {
            int idx = rep * 256 + tid;
            int d = idx >> 3, kc = (idx & 7) * 8;
            u16x8 vh, vl;
            #pragma unroll
            for (int q = 0; q < 8; ++q) {
                float f = tile[(kc + q) * 133 + d];
                unsigned short hi = f2bf(f);
                vh[q] = hi;
                vl[q] = f2bf(f - b2f(hi));
            }
            size_t o = (size_t)(h * 128 + d) * 1024 + k0 + kc;
            *(u16x8*)(Bh + o) = vh;
            *(u16x8*)(Bl + o) = vl;
        }
    } else if (bid < 512) {
        const int b2 = bid - 128;
        const int kt = b2 & 15, ht = b2 >> 4;
        const int h = ht & 7, t = ht >> 3;
        const int k0 = kt * 64;
        const float* wsrc = W + ((size_t)((h * 3 + t) * 1024) + k0) * 128;

        #pragma unroll
        for (int rep = 0; rep < 8; ++rep) {
            int idx = rep * 256 + tid;
            int k = idx >> 5, dc = (idx & 31) * 4;
            float4 v = *(const float4*)(wsrc + (size_t)k * 128 + dc);
            tile[k * 133 + dc + 0] = v.x;
            tile[k * 133 + dc + 1] = v.y;
            tile[k * 133 + dc + 2] = v.z;
            tile[k * 133 + dc + 3] = v.w;
        }
        __syncthreads();
        if (tid < 128) {
            const int k = tid & 63, s = tid >> 6;
            const float* ar = (s ? a2 : a1) + (h * 3 + t) * 128;
            float acc = 0.f;
            #pragma unroll 4
            for (int d = 0; d < 128; ++d) acc += tile[k * 133 + d] * ar[d];
            unsigned short hi = f2bf(acc);
            size_t o = (size_t)(1024 + s * 24 + t * 8 + h) * 1024 + k0 + k;
            Bh[o] = hi;
            Bl[o] = f2bf(acc - b2f(hi));
        }
    } else {
        const int n = 1072 + (bid - 512);
        *(unsigned long long*)(Bh + (size_t)n * 1024 + tid * 4) = 0ull;
        *(unsigned long long*)(Bl + (size_t)n * 1024 + tid * 4) = 0ull;
    }
}

// ---------------------------------------------------------------------------
// Kernel 2: bf16x3 MFMA GEMM — r14 structure (proven 89us); A-convert now
//   uses hardware cvt (f2bf_rn) to shorten the serial stage chain.
// ---------------------------------------------------------------------------
__global__ __launch_bounds__(256, 3) void mgemm(const float* __restrict__ X,
                                                const unsigned short* __restrict__ Bh,
                                                const unsigned short* __restrict__ Bl,
                                                const float* __restrict__ nm,
                                                unsigned short* __restrict__ Vt,
                                                float* __restrict__ LR) {
    __shared__ unsigned short Ah[128 * 32];
    __shared__ unsigned short Al[128 * 32];
    __shared__ unsigned short Bhs[128 * 32];
    __shared__ unsigned short Bls[128 * 32];

    const int bid = blockIdx.x;                 // 0..575
    const int swz = (bid & 7) * 72 + (bid >> 3); // XCD-aware, bijective
    const int nt = swz % 9, mt = swz / 9;
    const int n0 = nt * 128, m0 = mt * 128;

    const int tid = threadIdx.x;
    const int lane = tid & 63, w = tid >> 6;
    const int wr = w >> 1, wc = w & 1;
    const int fr = lane & 15, fq = lane >> 4;

    f32x4 acc[4][4];
    #pragma unroll
    for (int m = 0; m < 4; ++m)
        #pragma unroll
        for (int n = 0; n < 4; ++n) acc[m][n] = (f32x4){0.f, 0.f, 0.f, 0.f};

    const int arow = tid >> 1, ahalf = tid & 1;
    const float* xs = X + (size_t)(m0 + arow) * 1024 + ahalf * 16;
    unsigned short* adh = Ah + arow * 32 + ahalf * 16;
    unsigned short* adl = Al + arow * 32 + ahalf * 16;

    for (int k0 = 0; k0 < 1024; k0 += 32) {
        __syncthreads();

        #pragma unroll
        for (int q = 0; q < 2; ++q) {
            const int s = q * 256 + tid;
            const int brow = s >> 2, bkb = s & 3;
            const unsigned short* gh = Bh + (size_t)(n0 + brow) * 1024 + k0 + bkb * 8;
            const unsigned short* gl = Bl + (size_t)(n0 + brow) * 1024 + k0 + bkb * 8;
            unsigned short* dh = Bhs + (q * 256 + w * 64) * 8;
            unsigned short* dl = Bls + (q * 256 + w * 64) * 8;
            __builtin_amdgcn_global_load_lds(
                (const __attribute__((address_space(1))) void*)gh,
                (__attribute__((address_space(3))) void*)dh, 16, 0, 0);
            __builtin_amdgcn_global_load_lds(
                (const __attribute__((address_space(1))) void*)gl,
                (__attribute__((address_space(3))) void*)dl, 16, 0, 0);
        }

        float xf[16];
        #pragma unroll
        for (int i = 0; i < 4; ++i) {
            float4 v = *(const float4*)(xs + k0 + i * 4);
            xf[i * 4 + 0] = v.x; xf[i * 4 + 1] = v.y;
            xf[i * 4 + 2] = v.z; xf[i * 4 + 3] = v.w;
        }
        u16x8 vh0, vh1, vl0, vl1;
        #pragma unroll
        for (int i = 0; i < 8; ++i) {
            unsigned short hi = f2bf_rn(xf[i]);
            vh0[i] = hi;
            vl0[i] = f2bf_rn(xf[i] - b2f(hi));
        }
        #pragma unroll
        for (int i = 0; i < 8; ++i) {
            unsigned short hi = f2bf_rn(xf[8 + i]);
            vh1[i] = hi;
            vl1[i] = f2bf_rn(xf[8 + i] - b2f(hi));
        }
        *(u16x8*)(adh) = vh0;
        *(u16x8*)(adh + 8) = vh1;
        *(u16x8*)(adl) = vl0;
        *(u16x8*)(adl + 8) = vl1;

        __syncthreads();

        bf16x8 amh[4], bnh[4];
        #pragma unroll
        for (int m = 0; m < 4; ++m)
            amh[m] = *(bf16x8*)(Ah + (wr * 64 + m * 16 + fr) * 32 + fq * 8);
        #pragma unroll
        for (int n = 0; n < 4; ++n)
            bnh[n] = *(bf16x8*)(Bhs + (wc * 64 + n * 16 + fr) * 32 + fq * 8);
        #pragma unroll
        for (int m = 0; m < 4; ++m)
            #pragma unroll
            for (int n = 0; n < 4; ++n)
                acc[m][n] = __builtin_amdgcn_mfma_f32_16x16x32_bf16(amh[m], bnh[n], acc[m][n], 0, 0, 0);

        bf16x8 bnl[4];
        #pragma unroll
        for (int n = 0; n < 4; ++n)
            bnl[n] = *(bf16x8*)(Bls + (wc * 64 + n * 16 + fr) * 32 + fq * 8);
        #pragma unroll
        for (int m = 0; m < 4; ++m)
            #pragma unroll
            for (int n = 0; n < 4; ++n)
                acc[m][n] = __builtin_amdgcn_mfma_f32_16x16x32_bf16(amh[m], bnl[n], acc[m][n], 0, 0, 0);

        bf16x8 aml[4];
        #pragma unroll
        for (int m = 0; m < 4; ++m)
            aml[m] = *(bf16x8*)(Al + (wr * 64 + m * 16 + fr) * 32 + fq * 8);
        #pragma unroll
        for (int m = 0; m < 4; ++m)
            #pragma unroll
            for (int n = 0; n < 4; ++n)
                acc[m][n] = __builtin_amdgcn_mfma_f32_16x16x32_bf16(aml[m], bnh[n], acc[m][n], 0, 0, 0);
    }

    // ---- epilogue: C/D layout col=lane&15, row=(lane>>4)*4+reg
    if (nt < 8) {
        const int b_ = (mt * 128) >> 9;
        const int jb0 = (mt & 3) * 128;
        unsigned short* vtw = Vt + (size_t)(nt * 16 + b_) * 128 * 512;
        #pragma unroll
        for (int m = 0; m < 4; ++m) {
            const int jb = jb0 + wr * 64 + m * 16 + fq * 4;
            float mk[4];
            #pragma unroll
            for (int r = 0; r < 4; ++r)
                mk[r] = nm[m0 + wr * 64 + m * 16 + fq * 4 + r];
            #pragma unroll
            for (int n = 0; n < 4; ++n) {
                const int d = wc * 64 + n * 16 + fr;
                u16x4 pk;
                #pragma unroll
                for (int r = 0; r < 4; ++r) pk[r] = f2bf_rn(acc[m][n][r] * mk[r]);
                *(u16x4*)(vtw + (size_t)d * 512 + jb) = pk;
            }
        }
    } else {
        #pragma unroll
        for (int m = 0; m < 4; ++m) {
            #pragma unroll
            for (int r = 0; r < 4; ++r) {
                const int R = m0 + wr * 64 + m * 16 + fq * 4 + r;
                #pragma unroll
                for (int n = 0; n < 4; ++n) {
                    const int c = wc * 64 + n * 16 + fr;
                    if (c < 48) LR[(size_t)c * 8192 + R] = acc[m][n][r];
                }
            }
        }
    }
}

// ---------------------------------------------------------------------------
// Kernel 3b: adj int32 -> byte array adjB  [verified, unchanged]
// ---------------------------------------------------------------------------
__global__ __launch_bounds__(256) void adjb_kernel(const int* __restrict__ adj,
                                                   unsigned char* __restrict__ adjB) {
    const int idx = blockIdx.x * 256 + threadIdx.x;
    const int4* s = (const int4*)(adj + (size_t)idx * 16);
    int4 v0 = s[0], v1 = s[1], v2 = s[2], v3 = s[3];
    union { unsigned char c[16]; int4 v; } o;
    o.c[0] = (unsigned char)v0.x; o.c[1] = (unsigned char)v0.y;
    o.c[2] = (unsigned char)v0.z; o.c[3] = (unsigned char)v0.w;
    o.c[4] = (unsigned char)v1.x; o.c[5] = (unsigned char)v1.y;
    o.c[6] = (unsigned char)v1.z; o.c[7] = (unsigned char)v1.w;
    o.c[8] = (unsigned char)v2.x; o.c[9] = (unsigned char)v2.y;
    o.c[10] = (unsigned char)v2.z; o.c[11] = (unsigned char)v2.w;
    o.c[12] = (unsigned char)v3.x; o.c[13] = (unsigned char)v3.y;
    o.c[14] = (unsigned char)v3.z; o.c[15] = (unsigned char)v3.w;
    *(int4*)(adjB + (size_t)idx * 16) = o.v;
}

// ---------------------------------------------------------------------------
// Kernel 4: fused attn — r10 structure (verified); P conversion now uses
//   hardware cvt (f2bf_rn) to cut score-phase VALU ~30%.
// ---------------------------------------------------------------------------
__global__ __launch_bounds__(256, 4) void attn_kernel(const unsigned short* __restrict__ Vt,
                                                      const float* __restrict__ LR,
                                                      const unsigned char* __restrict__ adjB,
                                                      float* __restrict__ out) {
    __shared__ __align__(16) unsigned short Vb[2][16 * 512];
    __shared__ __align__(16) float rt[3 * 512];

    const int bid = blockIdx.x;
    const int itg = bid >> 7, hb = bid & 127, h = hb >> 4, b = hb & 15;
    const int tid = threadIdx.x, w = tid >> 6, lane = tid & 63;
    const int fr = lane & 15, fq = lane >> 4;
    const int i0 = (itg * 4 + w) * 16;
    const int fq8 = fq * 8;

    for (int idx = tid; idx < 1536; idx += 256) {
        int t = idx >> 9, j = idx & 511;
        rt[idx] = LR[(size_t)(24 + t * 8 + h) * 8192 + b * 512 + j];
    }
    const float lf0 = LR[(size_t)(h) * 8192 + b * 512 + i0 + fr];
    const float lf1 = LR[(size_t)(8 + h) * 8192 + b * 512 + i0 + fr];
    const float lf2 = LR[(size_t)(16 + h) * 8192 + b * 512 + i0 + fr];
    const unsigned char* arow = adjB + (size_t)(b * 512 + i0 + fr) * 512;
    const unsigned short* vt = Vt + (size_t)(h * 16 + b) * 128 * 512;

#define STAGE_V(bufp, os_) do {                                                   \
        _Pragma("unroll")                                                          \
        for (int q_ = 0; q_ < 4; ++q_) {                                           \
            const int nh_ = q_ * 4 + w;                                            \
            const unsigned short* src_ = vt + (size_t)((nh_ >> 1) * 16 + fr) * 512 \
                                          + (os_) * 64 + (nh_ & 1) * 32 + fq8;     \
            unsigned short* dst_ = (bufp) + nh_ * 512;                             \
            __builtin_amdgcn_global_load_lds(                                      \
                (const __attribute__((address_space(1))) void*)src_,               \
                (__attribute__((address_space(3))) void*)dst_, 16, 0, 0);          \
        }                                                                          \
    } while (0)

    STAGE_V(&Vb[0][0], 0);
    uint2 aA = *(const uint2*)(arow + fq8);
    uint2 aB = *(const uint2*)(arow + fq8 + 32);

    f32x4 acc[8];
    #pragma unroll
    for (int n = 0; n < 8; ++n) acc[n] = (f32x4){0.f, 0.f, 0.f, 0.f};
    float rsum = 0.f;

    __syncthreads();

    #pragma unroll 1
    for (int os = 0; os < 8; ++os) {
        unsigned short* vb = &Vb[os & 1][0];
        if (os < 7) STAGE_V(&Vb[(os & 1) ^ 1][0], os + 1);

        const int jA = os * 64 + fq8;
        const int jB = jA + 32;

        u16x8 vhA, vlA, vhB, vlB;
        {
            float4 r0a = *(const float4*)(rt + jA), r0b = *(const float4*)(rt + jA + 4);
            float4 r1a = *(const float4*)(rt + 512 + jA), r1b = *(const float4*)(rt + 512 + jA + 4);
            float4 r2a = *(const float4*)(rt + 1024 + jA), r2b = *(const float4*)(rt + 1024 + jA + 4);
            float e0[8] = {r0a.x, r0a.y, r0a.z, r0a.w, r0b.x, r0b.y, r0b.z, r0b.w};
            float e1[8] = {r1a.x, r1a.y, r1a.z, r1a.w, r1b.x, r1b.y, r1b.z, r1b.w};
            float e2[8] = {r2a.x, r2a.y, r2a.z, r2a.w, r2b.x, r2b.y, r2b.z, r2b.w};
            #pragma unroll
            for (int q = 0; q < 8; ++q) {
                unsigned av = ((q < 4 ? aA.x : aA.y) >> (8 * (q & 3))) & 255u;
                float sb = (av == 1u) ? (lf0 + e0[q])
                         : (av == 2u) ? (lf1 + e1[q]) : (lf2 + e2[q]);
                float sv = fmaxf(sb, 0.f) + 0.2f * fminf(sb, 0.f);
                float p = (av != 0u) ? __expf(sv) : 0.f;
                rsum += p;
                unsigned short hi = f2bf_rn(p);
                vhA[q] = hi;
                vlA[q] = f2bf_rn(p - b2f(hi));
            }
        }
        {
            float4 r0a = *(const float4*)(rt + jB), r0b = *(const float4*)(rt + jB + 4);
            float4 r1a = *(const float4*)(rt + 512 + jB), r1b = *(const float4*)(rt + 512 + jB + 4);
            float4 r2a = *(const float4*)(rt + 1024 + jB), r2b = *(const float4*)(rt + 1024 + jB + 4);
            float e0[8] = {r0a.x, r0a.y, r0a.z, r0a.w, r0b.x, r0b.y, r0b.z, r0b.w};
            float e1[8] = {r1a.x, r1a.y, r1a.z, r1a.w, r1b.x, r1b.y, r1b.z, r1b.w};
            float e2[8] = {r2a.x, r2a.y, r2a.z, r2a.w, r2b.x, r2b.y, r2b.z, r2b.w};
            #pragma unroll
            for (int q = 0; q < 8; ++q) {
                unsigned av = ((q < 4 ? aB.x : aB.y) >> (8 * (q & 3))) & 255u;
                float sb = (av == 1u) ? (lf0 + e0[q])
                         : (av == 2u) ? (lf1 + e1[q]) : (lf2 + e2[q]);
                float sv = fmaxf(sb, 0.f) + 0.2f * fminf(sb, 0.f);
                float p = (av != 0u) ? __expf(sv) : 0.f;
                rsum += p;
                unsigned short hi = f2bf_rn(p);
                vhB[q] = hi;
                vlB[q] = f2bf_rn(p - b2f(hi));
            }
        }
        if (os < 7) {
            aA = *(const uint2*)(arow + (os + 1) * 64 + fq8);
            aB = *(const uint2*)(arow + (os + 1) * 64 + fq8 + 32);
        }

        bf16x8 ahA = *(bf16x8*)&vhA, alA = *(bf16x8*)&vlA;
        bf16x8 ahB = *(bf16x8*)&vhB, alB = *(bf16x8*)&vlB;

        #pragma unroll
        for (int n = 0; n < 8; ++n) {
            bf16x8 vA = *(bf16x8*)(vb + (n * 2 + 0) * 512 + lane * 8);
            bf16x8 vB = *(bf16x8*)(vb + (n * 2 + 1) * 512 + lane * 8);
            acc[n] = __builtin_amdgcn_mfma_f32_16x16x32_bf16(ahA, vA, acc[n], 0, 0, 0);
            acc[n] = __builtin_amdgcn_mfma_f32_16x16x32_bf16(alA, vA, acc[n], 0, 0, 0);
            acc[n] = __builtin_amdgcn_mfma_f32_16x16x32_bf16(ahB, vB, acc[n], 0, 0, 0);
            acc[n] = __builtin_amdgcn_mfma_f32_16x16x32_bf16(alB, vB, acc[n], 0, 0, 0);
        }
        __syncthreads();
    }
#undef STAGE_V

    rsum += __shfl_xor(rsum, 16);
    rsum += __shfl_xor(rsum, 32);

    #pragma unroll
    for (int rr = 0; rr < 4; ++rr) {
        const int row = fq * 4 + rr;
        const float inv = 1.0f / __shfl(rsum, row);
        #pragma unroll
        for (int n = 0; n < 8; ++n) {
            out[(size_t)(b * 512 + i0 + row) * 1024 + h * 128 + n * 16 + fr] =
                fmaxf(acc[n][rr] * inv, 0.f);
        }
    }
}

// ---------------------------------------------------------------------------
extern "C" void kernel_launch(void* const* d_in, const int* in_sizes, int n_in,
                              void* d_out, int out_size, void* d_ws, size_t ws_size,
                              hipStream_t stream) {
    const float* x   = (const float*)d_in[0];
    const int*   adj = (const int*)d_in[1];
    const float* nm  = (const float*)d_in[2];
    const float* W   = (const float*)d_in[3];
    const float* a1  = (const float*)d_in[4];
    const float* a2  = (const float*)d_in[5];
    float* out = (float*)d_out;
    char* wsb = (char*)d_ws;

    unsigned short* Bh   = (unsigned short*)(wsb);
    unsigned short* Bl   = (unsigned short*)(wsb + 2359296);
    float*          LR   = (float*)(wsb + 21495808);
    unsigned short* Vt   = (unsigned short*)(wsb + 23068672);
    unsigned char*  adjB = (unsigned char*)(wsb + 39845888);

    hipLaunchKernelGGL(adjb_kernel, dim3(1024), dim3(256), 0, stream, adj, adjB);
    hipLaunchKernelGGL(pack_all, dim3(592), dim3(256), 0, stream, W, a1, a2, Bh, Bl);
    hipLaunchKernelGGL(mgemm, dim3(576), dim3(256), 0, stream, x, Bh, Bl, nm, Vt, LR);
    hipLaunchKernelGGL(attn_kernel, dim3(1024), dim3(256), 0, stream, Vt, LR, adjB, out);
}